// Round 1
// baseline (387.419 us; speedup 1.0000x reference)
//
#include <hip/hip_runtime.h>

#define NELEM (4096 * 4096)
#define KDIM 4096
#define NDIM 4096
#define DOUT 4096
#define EPSQ 1e-8f

typedef __attribute__((ext_vector_type(8))) short bf16x8;
typedef __attribute__((ext_vector_type(4))) float f32x4;

typedef __attribute__((address_space(3))) void lds_void;
typedef const __attribute__((address_space(1))) void gbl_void;

__device__ __forceinline__ void load_lds16(const short* g, short* l) {
    __builtin_amdgcn_global_load_lds((gbl_void*)g, (lds_void*)l, 16, 0, 0);
}

__device__ __forceinline__ float wave_max64(float v) {
#pragma unroll
    for (int off = 32; off > 0; off >>= 1)
        v = fmaxf(v, __shfl_down(v, off));
    return v;
}

// ---------------- kernel 1: zero absmax slots ----------------
__global__ void zero_ws(unsigned* __restrict__ amax) {
    if (threadIdx.x < 4) amax[threadIdx.x] = 0u;
}

// ---------------- kernel 2: fused absmax of x, w, b ----------------
__global__ __launch_bounds__(256) void absmax_xwb(
    const float4* __restrict__ x, const float4* __restrict__ w,
    const float* __restrict__ b, unsigned* __restrict__ amax)
{
    const int n4 = NELEM / 4;
    float mx = 0.f, mw = 0.f;
    for (int i = blockIdx.x * 256 + threadIdx.x; i < n4; i += gridDim.x * 256) {
        float4 a = x[i];
        mx = fmaxf(mx, fmaxf(fmaxf(fabsf(a.x), fabsf(a.y)), fmaxf(fabsf(a.z), fabsf(a.w))));
        float4 c = w[i];
        mw = fmaxf(mw, fmaxf(fmaxf(fabsf(c.x), fabsf(c.y)), fmaxf(fabsf(c.z), fabsf(c.w))));
    }
    float mb = 0.f;
    if (blockIdx.x == 0)
        for (int i = threadIdx.x; i < DOUT; i += 256) mb = fmaxf(mb, fabsf(b[i]));

    mx = wave_max64(mx); mw = wave_max64(mw); mb = wave_max64(mb);
    __shared__ float red[3][4];
    const int wave = threadIdx.x >> 6, lane = threadIdx.x & 63;
    if (lane == 0) { red[0][wave] = mx; red[1][wave] = mw; red[2][wave] = mb; }
    __syncthreads();
    if (threadIdx.x == 0) {
        float r0 = fmaxf(fmaxf(red[0][0], red[0][1]), fmaxf(red[0][2], red[0][3]));
        float r1 = fmaxf(fmaxf(red[1][0], red[1][1]), fmaxf(red[1][2], red[1][3]));
        atomicMax(&amax[0], __float_as_uint(r0));
        atomicMax(&amax[1], __float_as_uint(r1));
        if (blockIdx.x == 0) {
            float r2 = fmaxf(fmaxf(red[2][0], red[2][1]), fmaxf(red[2][2], red[2][3]));
            atomicMax(&amax[2], __float_as_uint(r2));
        }
    }
}

// quantize one float to its integer level, return bf16 bits (exact: |q| <= 127)
__device__ __forceinline__ short quant_bits(float v, float s, float qmax) {
    float q = rintf(v / s);              // IEEE div + round-half-even == jnp.round(t/scale)
    q = fminf(fmaxf(q, -qmax), qmax);
    return (short)(__float_as_uint(q) >> 16);  // exact bf16 (low 16 mantissa bits are 0)
}

// ---------------- kernel 3: fused quantize x -> q_x(bf16), w -> q_w(bf16), b -> bq(f32) ----------------
__global__ __launch_bounds__(256) void quant_xwb(
    const float4* __restrict__ x, const float4* __restrict__ w,
    const float* __restrict__ b, const unsigned* __restrict__ amax,
    short4* __restrict__ qx, short4* __restrict__ qw, float* __restrict__ bq)
{
    const float sx = fmaxf(__uint_as_float(amax[0]) / 127.0f, EPSQ);
    const float sw = fmaxf(__uint_as_float(amax[1]) / 7.0f, EPSQ);
    const int n4 = NELEM / 4;
    for (int i = blockIdx.x * 256 + threadIdx.x; i < n4; i += gridDim.x * 256) {
        float4 a = x[i];
        short4 o;
        o.x = quant_bits(a.x, sx, 127.f); o.y = quant_bits(a.y, sx, 127.f);
        o.z = quant_bits(a.z, sx, 127.f); o.w = quant_bits(a.w, sx, 127.f);
        qx[i] = o;
        float4 c = w[i];
        short4 p;
        p.x = quant_bits(c.x, sw, 7.f); p.y = quant_bits(c.y, sw, 7.f);
        p.z = quant_bits(c.z, sw, 7.f); p.w = quant_bits(c.w, sw, 7.f);
        qw[i] = p;
    }
    if (blockIdx.x == 0) {
        const float sb = fmaxf(__uint_as_float(amax[2]) / 127.0f, EPSQ);
        for (int i = threadIdx.x; i < DOUT; i += 256) {
            float q = fminf(fmaxf(rintf(b[i] / sb), -127.f), 127.f);
            bq[i] = q * sb;
        }
    }
}

// ---------------- kernel 4: bf16 MFMA GEMM (m97 structure), fused epilogue ----------------
// C[m,n] = bq[n] + s * sum_k qx[m,k]*qw[n,k];  also absmax(C) -> amax_out
__global__ __launch_bounds__(256, 2) void gemm_bt(
    const short* __restrict__ qx,   // bf16 bits [4096][4096] (M,K)
    const short* __restrict__ qw,   // bf16 bits [4096][4096] (N,K)
    const float* __restrict__ bq,
    const unsigned* __restrict__ amax,
    float* __restrict__ out,
    unsigned* __restrict__ amax_out)
{
    constexpr int K = KDIM, N = NDIM, BK = 32;
    __shared__ short smemA[128 * BK];   // 8 KB, row-major [128][32], NO padding (global_load_lds)
    __shared__ short smemB[128 * BK];   // 8 KB
    __shared__ float red[4];

    const int tid = threadIdx.x;
    const int wave = tid >> 6;
    const int lane = tid & 63;
    const int bm = blockIdx.y, bn = blockIdx.x;

    const int wm = (wave & 1) * 64;     // wave's 64x64 quadrant
    const int wn = (wave >> 1) * 64;

    f32x4 acc[4][4] = {};

    // staging: each wave stages 16 rows per issue; lane -> (row = 16*chunk + lane/4, col8 = lane%4)
    const int srow = wave * 16 + (lane >> 2);
    const int scol = (lane & 3) * 8;
    const short* aP0 = qx + (bm * 128 + srow) * K + scol;
    const short* aP1 = aP0 + 64 * K;
    const short* bP0 = qw + (bn * 128 + srow) * K + scol;
    const short* bP1 = bP0 + 64 * K;
    short* aL0 = smemA + wave * 512;   // wave-uniform LDS dst, lane*16B appended by HW
    short* aL1 = aL0 + 2048;
    short* bL0 = smemB + wave * 512;
    short* bL1 = bL0 + 2048;

    const int frow = lane & 15;         // fragment row/col within 16x16
    const int fk = (lane >> 4) * 8;     // k-offset of this lane's 8 elements

    for (int k0 = 0; k0 < K; k0 += BK) {
        __syncthreads();                 // previous tile's MFMAs done before overwrite
        load_lds16(aP0 + k0, aL0);
        load_lds16(aP1 + k0, aL1);
        load_lds16(bP0 + k0, bL0);
        load_lds16(bP1 + k0, bL1);
        __syncthreads();                 // compiler drains vmcnt(0) before barrier

        bf16x8 af[4], bf[4];
#pragma unroll
        for (int i = 0; i < 4; ++i)
            af[i] = *(const bf16x8*)(smemA + (wm + i * 16 + frow) * BK + fk);
#pragma unroll
        for (int j = 0; j < 4; ++j)
            bf[j] = *(const bf16x8*)(smemB + (wn + j * 16 + frow) * BK + fk);
#pragma unroll
        for (int i = 0; i < 4; ++i)
#pragma unroll
            for (int j = 0; j < 4; ++j)
                acc[i][j] = __builtin_amdgcn_mfma_f32_16x16x32_bf16(af[i], bf[j], acc[i][j], 0, 0, 0);
    }

    // epilogue: C/D layout col=lane&15, row=(lane>>4)*4+reg  [m89/m91-verified]
    const float sx = fmaxf(__uint_as_float(amax[0]) / 127.0f, EPSQ);
    const float sw = fmaxf(__uint_as_float(amax[1]) / 7.0f, EPSQ);
    const float s = sx * sw;
    const int col = lane & 15;
    const int rbase = (lane >> 4) * 4;
    float am = 0.f;
    float bqv[4];
#pragma unroll
    for (int j = 0; j < 4; ++j) bqv[j] = bq[bn * 128 + wn + j * 16 + col];

#pragma unroll
    for (int i = 0; i < 4; ++i) {
#pragma unroll
        for (int r = 0; r < 4; ++r) {
            const int m = bm * 128 + wm + i * 16 + rbase + r;
            float* orow = out + (long)m * N + bn * 128 + wn + col;
#pragma unroll
            for (int j = 0; j < 4; ++j) {
                float o = fmaf(s, acc[i][j][r], bqv[j]);
                am = fmaxf(am, fabsf(o));
                orow[j * 16] = o;
            }
        }
    }
    am = wave_max64(am);
    if (lane == 0) red[wave] = am;
    __syncthreads();
    if (tid == 0)
        atomicMax(amax_out, __float_as_uint(fmaxf(fmaxf(red[0], red[1]), fmaxf(red[2], red[3]))));
}

// ---------------- kernel 5: in-place final fake-quant of out ----------------
__global__ __launch_bounds__(256) void final_quant(
    float4* __restrict__ out, const unsigned* __restrict__ amax)
{
    const float so = fmaxf(__uint_as_float(amax[3]) / 127.0f, EPSQ);
    const int n4 = NELEM / 4;
    for (int i = blockIdx.x * 256 + threadIdx.x; i < n4; i += gridDim.x * 256) {
        float4 v = out[i];
        v.x = fminf(fmaxf(rintf(v.x / so), -127.f), 127.f) * so;
        v.y = fminf(fmaxf(rintf(v.y / so), -127.f), 127.f) * so;
        v.z = fminf(fmaxf(rintf(v.z / so), -127.f), 127.f) * so;
        v.w = fminf(fmaxf(rintf(v.w / so), -127.f), 127.f) * so;
        out[i] = v;
    }
}

extern "C" void kernel_launch(void* const* d_in, const int* in_sizes, int n_in,
                              void* d_out, int out_size, void* d_ws, size_t ws_size,
                              hipStream_t stream) {
    const float* x = (const float*)d_in[0];   // [4096,4096]
    const float* w = (const float*)d_in[1];   // [4096,4096] (out,in)
    const float* b = (const float*)d_in[2];   // [4096]
    float* out = (float*)d_out;               // [4096,4096] fp32

    char* ws = (char*)d_ws;
    unsigned* amax = (unsigned*)ws;                         // [0]=x,[1]=w,[2]=b,[3]=out
    float* bq = (float*)(ws + 256);                         // 16 KB
    short* qx = (short*)(ws + 32768);                       // 32 MB (bf16 bits)
    short* qw = (short*)(ws + 32768 + (size_t)NELEM * 2);   // 32 MB

    hipLaunchKernelGGL(zero_ws, dim3(1), dim3(64), 0, stream, amax);
    hipLaunchKernelGGL(absmax_xwb, dim3(2048), dim3(256), 0, stream,
                       (const float4*)x, (const float4*)w, b, amax);
    hipLaunchKernelGGL(quant_xwb, dim3(2048), dim3(256), 0, stream,
                       (const float4*)x, (const float4*)w, b, amax,
                       (short4*)qx, (short4*)qw, bq);
    hipLaunchKernelGGL(gemm_bt, dim3(32, 32), dim3(256), 0, stream,
                       qx, qw, bq, amax, out, amax + 3);
    hipLaunchKernelGGL(final_quant, dim3(2048), dim3(256), 0, stream,
                       (float4*)out, amax);
}

// Round 2
// 317.732 us; speedup vs baseline: 1.2193x; 1.2193x over previous
//
#include <hip/hip_runtime.h>

#define NELEM (4096 * 4096)
#define KDIM 4096
#define NDIM 4096
#define DOUT 4096
#define EPSQ 1e-8f

typedef __attribute__((ext_vector_type(4))) int i32x4;

typedef __attribute__((address_space(3))) void lds_void;
typedef const __attribute__((address_space(1))) void gbl_void;

__device__ __forceinline__ void load_lds16(const void* g, void* l) {
    __builtin_amdgcn_global_load_lds((gbl_void*)g, (lds_void*)l, 16, 0, 0);
}

__device__ __forceinline__ float wave_max64(float v) {
#pragma unroll
    for (int off = 32; off > 0; off >>= 1)
        v = fmaxf(v, __shfl_down(v, off));
    return v;
}

// ---------------- kernel 1: zero absmax slots ----------------
__global__ void zero_ws(unsigned* __restrict__ amax) {
    if (threadIdx.x < 4) amax[threadIdx.x] = 0u;
}

// ---------------- kernel 2: fused absmax of x, w, b ----------------
__global__ __launch_bounds__(256) void absmax_xwb(
    const float4* __restrict__ x, const float4* __restrict__ w,
    const float* __restrict__ b, unsigned* __restrict__ amax)
{
    const int n4 = NELEM / 4;
    float mx = 0.f, mw = 0.f;
    for (int i = blockIdx.x * 256 + threadIdx.x; i < n4; i += gridDim.x * 256) {
        float4 a = x[i];
        mx = fmaxf(mx, fmaxf(fmaxf(fabsf(a.x), fabsf(a.y)), fmaxf(fabsf(a.z), fabsf(a.w))));
        float4 c = w[i];
        mw = fmaxf(mw, fmaxf(fmaxf(fabsf(c.x), fabsf(c.y)), fmaxf(fabsf(c.z), fabsf(c.w))));
    }
    float mb = 0.f;
    if (blockIdx.x == 0)
        for (int i = threadIdx.x; i < DOUT; i += 256) mb = fmaxf(mb, fabsf(b[i]));

    mx = wave_max64(mx); mw = wave_max64(mw); mb = wave_max64(mb);
    __shared__ float red[3][4];
    const int wave = threadIdx.x >> 6, lane = threadIdx.x & 63;
    if (lane == 0) { red[0][wave] = mx; red[1][wave] = mw; red[2][wave] = mb; }
    __syncthreads();
    if (threadIdx.x == 0) {
        float r0 = fmaxf(fmaxf(red[0][0], red[0][1]), fmaxf(red[0][2], red[0][3]));
        float r1 = fmaxf(fmaxf(red[1][0], red[1][1]), fmaxf(red[1][2], red[1][3]));
        atomicMax(&amax[0], __float_as_uint(r0));
        atomicMax(&amax[1], __float_as_uint(r1));
        if (blockIdx.x == 0) {
            float r2 = fmaxf(fmaxf(red[2][0], red[2][1]), fmaxf(red[2][2], red[2][3]));
            atomicMax(&amax[2], __float_as_uint(r2));
        }
    }
}

// quantize 4 floats to int8 levels, pack into one int32
__device__ __forceinline__ int pack4(float4 a, float s, float qmax) {
    int b0 = (int)fminf(fmaxf(rintf(a.x / s), -qmax), qmax);  // rintf = round-half-even = jnp.round
    int b1 = (int)fminf(fmaxf(rintf(a.y / s), -qmax), qmax);
    int b2 = (int)fminf(fmaxf(rintf(a.z / s), -qmax), qmax);
    int b3 = (int)fminf(fmaxf(rintf(a.w / s), -qmax), qmax);
    return (b0 & 0xff) | ((b1 & 0xff) << 8) | ((b2 & 0xff) << 16) | (b3 << 24);
}

// ---------------- kernel 3: fused quantize x -> q_x(i8), w -> q_w(i8), b -> bq(f32) ----------------
__global__ __launch_bounds__(256) void quant_xwb(
    const float4* __restrict__ x, const float4* __restrict__ w,
    const float* __restrict__ b, const unsigned* __restrict__ amax,
    int4* __restrict__ qx, int4* __restrict__ qw, float* __restrict__ bq)
{
    const float sx = fmaxf(__uint_as_float(amax[0]) / 127.0f, EPSQ);
    const float sw = fmaxf(__uint_as_float(amax[1]) / 7.0f, EPSQ);
    const int n16 = NELEM / 16;   // each thread-iter: 16 floats -> 16 int8 (one int4 store)
    for (int i = blockIdx.x * 256 + threadIdx.x; i < n16; i += gridDim.x * 256) {
        int4 r;
        r.x = pack4(x[i * 4 + 0], sx, 127.f);
        r.y = pack4(x[i * 4 + 1], sx, 127.f);
        r.z = pack4(x[i * 4 + 2], sx, 127.f);
        r.w = pack4(x[i * 4 + 3], sx, 127.f);
        qx[i] = r;
        int4 p;
        p.x = pack4(w[i * 4 + 0], sw, 7.f);
        p.y = pack4(w[i * 4 + 1], sw, 7.f);
        p.z = pack4(w[i * 4 + 2], sw, 7.f);
        p.w = pack4(w[i * 4 + 3], sw, 7.f);
        qw[i] = p;
    }
    if (blockIdx.x == 0) {
        const float sb = fmaxf(__uint_as_float(amax[2]) / 127.0f, EPSQ);
        for (int i = threadIdx.x; i < DOUT; i += 256) {
            float q = fminf(fmaxf(rintf(b[i] / sb), -127.f), 127.f);
            bq[i] = q * sb;
        }
    }
}

// ---------------- kernel 4: i8 MFMA GEMM (m97 structure, BK=64), fused epilogue ----------------
// C[m,n] = bq[n] + s * sum_k qx[m,k]*qw[n,k] (exact i32 accumulate);  absmax(C) -> amax_out
__global__ __launch_bounds__(256, 2) void gemm_i8(
    const char* __restrict__ qx,   // int8 [4096][4096] (M,K)
    const char* __restrict__ qw,   // int8 [4096][4096] (N,K)
    const float* __restrict__ bq,
    const unsigned* __restrict__ amax,
    float* __restrict__ out,
    unsigned* __restrict__ amax_out)
{
    constexpr int K = KDIM, N = NDIM, BK = 64;  // BK in i8 elements (64 B rows)
    __shared__ char smemA[128 * BK];   // 8 KB, row-major [128][64], NO padding (global_load_lds)
    __shared__ char smemB[128 * BK];   // 8 KB
    __shared__ float red[4];

    const int tid = threadIdx.x;
    const int wave = tid >> 6;
    const int lane = tid & 63;
    const int bm = blockIdx.y, bn = blockIdx.x;

    const int wm = (wave & 1) * 64;     // wave's 64x64 quadrant
    const int wn = (wave >> 1) * 64;

    i32x4 acc[4][4] = {};

    // staging: wave stages 16 rows/issue; lane -> (row = lane/4, byte-col = (lane%4)*16)
    const int srow = wave * 16 + (lane >> 2);
    const int scol = (lane & 3) * 16;
    const char* aP0 = qx + (long)(bm * 128 + srow) * K + scol;
    const char* aP1 = aP0 + 64 * K;
    const char* bP0 = qw + (long)(bn * 128 + srow) * K + scol;
    const char* bP1 = bP0 + 64 * K;
    char* aL0 = smemA + wave * 1024;   // wave-uniform LDS dst, lane*16B appended by HW
    char* aL1 = aL0 + 4096;
    char* bL0 = smemB + wave * 1024;
    char* bL1 = bL0 + 4096;

    const int frow = lane & 15;         // fragment row within 16x16
    const int fk = (lane >> 4) * 16;    // byte k-offset of this lane's 16 i8 elements

    for (int k0 = 0; k0 < K; k0 += BK) {
        __syncthreads();                 // previous tile's MFMAs done before overwrite
        load_lds16(aP0 + k0, aL0);
        load_lds16(aP1 + k0, aL1);
        load_lds16(bP0 + k0, bL0);
        load_lds16(bP1 + k0, bL1);
        __syncthreads();                 // drains vmcnt(0) before barrier

        i32x4 af[4], bf[4];
#pragma unroll
        for (int i = 0; i < 4; ++i)
            af[i] = *(const i32x4*)(smemA + (wm + i * 16 + frow) * BK + fk);
#pragma unroll
        for (int j = 0; j < 4; ++j)
            bf[j] = *(const i32x4*)(smemB + (wn + j * 16 + frow) * BK + fk);
#pragma unroll
        for (int i = 0; i < 4; ++i)
#pragma unroll
            for (int j = 0; j < 4; ++j)
                acc[i][j] = __builtin_amdgcn_mfma_i32_16x16x64_i8(af[i], bf[j], acc[i][j], 0, 0, 0);
    }

    // epilogue: C/D layout col=lane&15, row=(lane>>4)*4+reg (shape-determined, dtype-independent)
    const float sx = fmaxf(__uint_as_float(amax[0]) / 127.0f, EPSQ);
    const float sw = fmaxf(__uint_as_float(amax[1]) / 7.0f, EPSQ);
    const float s = sx * sw;
    const int col = lane & 15;
    const int rbase = (lane >> 4) * 4;
    float am = 0.f;
    float bqv[4];
#pragma unroll
    for (int j = 0; j < 4; ++j) bqv[j] = bq[bn * 128 + wn + j * 16 + col];

#pragma unroll
    for (int i = 0; i < 4; ++i) {
#pragma unroll
        for (int r = 0; r < 4; ++r) {
            const int m = bm * 128 + wm + i * 16 + rbase + r;
            float* orow = out + (long)m * N + bn * 128 + wn + col;
#pragma unroll
            for (int j = 0; j < 4; ++j) {
                float o = fmaf(s, (float)acc[i][j][r], bqv[j]);  // exact: |acc| <= 3.6M < 2^24
                am = fmaxf(am, fabsf(o));
                orow[j * 16] = o;
            }
        }
    }
    am = wave_max64(am);
    if (lane == 0) red[wave] = am;
    __syncthreads();
    if (tid == 0)
        atomicMax(amax_out, __float_as_uint(fmaxf(fmaxf(red[0], red[1]), fmaxf(red[2], red[3]))));
}

// ---------------- kernel 5: in-place final fake-quant of out ----------------
__global__ __launch_bounds__(256) void final_quant(
    float4* __restrict__ out, const unsigned* __restrict__ amax)
{
    const float so = fmaxf(__uint_as_float(amax[3]) / 127.0f, EPSQ);
    const int n4 = NELEM / 4;
    for (int i = blockIdx.x * 256 + threadIdx.x; i < n4; i += gridDim.x * 256) {
        float4 v = out[i];
        v.x = fminf(fmaxf(rintf(v.x / so), -127.f), 127.f) * so;
        v.y = fminf(fmaxf(rintf(v.y / so), -127.f), 127.f) * so;
        v.z = fminf(fmaxf(rintf(v.z / so), -127.f), 127.f) * so;
        v.w = fminf(fmaxf(rintf(v.w / so), -127.f), 127.f) * so;
        out[i] = v;
    }
}

extern "C" void kernel_launch(void* const* d_in, const int* in_sizes, int n_in,
                              void* d_out, int out_size, void* d_ws, size_t ws_size,
                              hipStream_t stream) {
    const float* x = (const float*)d_in[0];   // [4096,4096]
    const float* w = (const float*)d_in[1];   // [4096,4096] (out,in)
    const float* b = (const float*)d_in[2];   // [4096]
    float* out = (float*)d_out;               // [4096,4096] fp32

    char* ws = (char*)d_ws;
    unsigned* amax = (unsigned*)ws;                         // [0]=x,[1]=w,[2]=b,[3]=out
    float* bq = (float*)(ws + 256);                         // 16 KB
    char* qx = (char*)(ws + 32768);                         // 16 MB int8
    char* qw = (char*)(ws + 32768 + (size_t)NELEM);         // 16 MB int8

    hipLaunchKernelGGL(zero_ws, dim3(1), dim3(64), 0, stream, amax);
    hipLaunchKernelGGL(absmax_xwb, dim3(2048), dim3(256), 0, stream,
                       (const float4*)x, (const float4*)w, b, amax);
    hipLaunchKernelGGL(quant_xwb, dim3(2048), dim3(256), 0, stream,
                       (const float4*)x, (const float4*)w, b, amax,
                       (int4*)qx, (int4*)qw, bq);
    hipLaunchKernelGGL(gemm_i8, dim3(32, 32), dim3(256), 0, stream,
                       qx, qw, bq, amax, out, amax + 3);
    hipLaunchKernelGGL(final_quant, dim3(2048), dim3(256), 0, stream,
                       (float4*)out, amax);
}